// Round 15
// baseline (193.820 us; speedup 1.0000x reference)
//
#include <hip/hip_runtime.h>

// SymHQLinear: out[8192,4096] = x @ W^T; W[4096,4096] dequantized from
// codebook[4096,8] + per-row scales + packed sign bits.
// Strategy: per-row symmetric i8 quantization, mfma_i32_16x16x64_i8 GEMM,
// fp32 epilogue scales.  R15: R11's exact 2-phase structure at HALF block
// size (256x128 tile, 4 waves, 48 KiB LDS) so TWO independent WGs co-reside
// per CU -- separate barrier domains let one WG's MFMA phase cover the
// other's LDS/stage phase (m114 co-scheduling, now across barrier domains).
#define M_ 8192   // TOKENS
#define N_ 4096   // OUT
#define K_ 4096   // IN

typedef float f32x4 __attribute__((ext_vector_type(4)));
typedef int   i32x4 __attribute__((ext_vector_type(4)));

// ---------------------------------------------------------------------------
// Kernel 1 (fused prep): blocks [0, 4096): W row -> dequant, row-max, i8 + sw
//                        blocks [4096, 12288): X row -> row-max, i8 + sx
// ---------------------------------------------------------------------------
__device__ __forceinline__ unsigned pack4(const float* v, float inv) {
  unsigned r = 0;
#pragma unroll
  for (int j = 0; j < 4; ++j) {
    int q = (int)rintf(v[j] * inv);
    q = q < -127 ? -127 : (q > 127 ? 127 : q);
    r |= ((unsigned)(q & 0xff)) << (8 * j);
  }
  return r;
}

__global__ __launch_bounds__(256) void prep_kernel(
    const float* __restrict__ x, const float* __restrict__ cb,
    const float* __restrict__ scales, const int* __restrict__ idx,
    const int* __restrict__ signs,
    signed char* __restrict__ Wq, signed char* __restrict__ Xq,
    float* __restrict__ sw, float* __restrict__ sx)
{
  __shared__ float wred[4];
  const int b = blockIdx.x, t = threadIdx.x;

  if (b < N_) {
    const float s = scales[b];
    const int g0 = b * 512 + t, g1 = g0 + 256;
    const int c0 = idx[g0], c1 = idx[g1];
    const int sb0 = signs[g0], sb1 = signs[g1];
    const float* cv0 = cb + c0 * 8;
    const float* cv1 = cb + c1 * 8;
    float v[16];
    float mx = 0.f;
#pragma unroll
    for (int j = 0; j < 8; ++j) {
      float a = cv0[j] * s;
      if (!((sb0 >> (7 - j)) & 1)) a = -a;
      v[j] = a; mx = fmaxf(mx, fabsf(a));
    }
#pragma unroll
    for (int j = 0; j < 8; ++j) {
      float a = cv1[j] * s;
      if (!((sb1 >> (7 - j)) & 1)) a = -a;
      v[8 + j] = a; mx = fmaxf(mx, fabsf(a));
    }
#pragma unroll
    for (int off = 1; off < 64; off <<= 1) mx = fmaxf(mx, __shfl_xor(mx, off));
    if ((t & 63) == 0) wred[t >> 6] = mx;
    __syncthreads();
    mx = fmaxf(fmaxf(wred[0], wred[1]), fmaxf(wred[2], wred[3]));
    mx = fmaxf(mx, 1e-20f);
    const float inv = 127.0f / mx;
    if (t == 0) sw[b] = mx / 127.0f;
    uint2 o0 = {pack4(v, inv),     pack4(v + 4, inv)};
    uint2 o1 = {pack4(v + 8, inv), pack4(v + 12, inv)};
    *(uint2*)(Wq + (size_t)b * K_ + t * 8)        = o0;
    *(uint2*)(Wq + (size_t)b * K_ + 2048 + t * 8) = o1;
  } else {
    const int r = b - N_;
    const f32x4* px = (const f32x4*)(x + (size_t)r * K_ + t * 16);
    f32x4 a0 = px[0], a1 = px[1], a2 = px[2], a3 = px[3];
    float v[16];
#pragma unroll
    for (int j = 0; j < 4; ++j) { v[j] = a0[j]; v[4 + j] = a1[j]; v[8 + j] = a2[j]; v[12 + j] = a3[j]; }
    float mx = 0.f;
#pragma unroll
    for (int j = 0; j < 16; ++j) mx = fmaxf(mx, fabsf(v[j]));
#pragma unroll
    for (int off = 1; off < 64; off <<= 1) mx = fmaxf(mx, __shfl_xor(mx, off));
    if ((t & 63) == 0) wred[t >> 6] = mx;
    __syncthreads();
    mx = fmaxf(fmaxf(wred[0], wred[1]), fmaxf(wred[2], wred[3]));
    mx = fmaxf(mx, 1e-20f);
    const float inv = 127.0f / mx;
    if (t == 0) sx[r] = mx / 127.0f;
    uint4 o = {pack4(v, inv), pack4(v + 4, inv), pack4(v + 8, inv), pack4(v + 12, inv)};
    *(uint4*)(Xq + (size_t)r * K_ + t * 16) = o;
  }
}

// ---------------------------------------------------------------------------
// Kernel 2: 256x128x64 i8 GEMM, 4 waves (2Mx2N), 2 phases/tile -- R11's
// structure at half block so 2 WGs/CU co-reside (independent barrier domains).
// LDS 48 KiB/WG: [2 bufs][A 256x64 @0 | B 128x64 @16384]; chunk swizzle
// c' = c ^ ((row>>1)&3) (R11, conflict-free, both-sides rule 21).
//   P0: read A-lo(4)+B(4); stage A(T+1)->nb (4 lines); BAR; lgkm0; 16 MFMA; BAR
//   P1: read A-hi(4);      stage B(T+2)->b  (2 lines); BAR; lgkm0; 16 MFMA;
//       vmcnt(2); BAR
// vmcnt ledger @ T P1-end (oldest first): [B(T+1):2][A(T+1):4][B(T+2):2]
// -> keep 2 drains ALL tile-(T+1) data.  Prologue [A0:4][B0:2][B1:2],
// vmcnt(2) drains tile 0.  T=NT-2: stage A only, vmcnt(0).  T=NT-1: none.
// WAR audit identical to R11 (each slot staged only after its last reader's
// lgkm0 + phase-end barrier).
// ---------------------------------------------------------------------------
#define BM 256
#define BN 128
#define BK 64
#define NT (K_ / BK)          // 64 K-tiles
#define BOFF 16384            // B region byte offset within a buffer

#define GLDS(g, l) __builtin_amdgcn_global_load_lds( \
    (const __attribute__((address_space(1))) void*)(g), \
    (__attribute__((address_space(3))) void*)(l), 16, 0, 0)

#define LGKM0 do { \
    asm volatile("s_waitcnt lgkmcnt(0)" ::: "memory"); \
    __builtin_amdgcn_sched_barrier(0); \
  } while (0)

#define VM_WAIT(n) asm volatile("s_waitcnt vmcnt(" #n ")" ::: "memory")
#define MEMFENCE asm volatile("" ::: "memory")

// MODE: 0 steady, 1 = T==NT-2, 2 = T==NT-1
template<int MODE>
__device__ __forceinline__ void tile_step(
    int T, signed char (*lds)[24576], i32x4 (&acc)[8][4],
    const signed char* __restrict__ Ag,
    const signed char* __restrict__ Bg,
    int wm, int wn, int lrow, int cs16,   // cs16 = (hi2 ^ ((lrow>>1)&3)) * 16
    int tid, int sr, int scs)             // scs = inv-swizzled staging col
{
  const int b = T & 1, nb = b ^ 1;
  i32x4 av[4], bv[4];

  // ================= P0: read A-lo(4)+B(4); stage A(T+1) =================
#pragma unroll
  for (int m = 0; m < 4; ++m)
    av[m] = *(const i32x4*)(const void*)(
        &lds[b][(wm * 128 + m * 16 + lrow) * 64 + cs16]);
#pragma unroll
  for (int n = 0; n < 4; ++n)
    bv[n] = *(const i32x4*)(const void*)(
        &lds[b][BOFF + (wn * 64 + n * 16 + lrow) * 64 + cs16]);
  if (MODE <= 1) {
#pragma unroll
    for (int L = 0; L < 4; ++L)
      GLDS(Ag + (size_t)(sr + L * 64) * K_ + (T + 1) * BK + scs,
           &lds[nb][L * 4096 + tid * 16]);
  }
  __builtin_amdgcn_s_barrier();
  LGKM0;
  __builtin_amdgcn_s_setprio(1);
#pragma unroll
  for (int n = 0; n < 4; ++n)
#pragma unroll
    for (int m = 0; m < 4; ++m)
      acc[m][n] = __builtin_amdgcn_mfma_i32_16x16x64_i8(av[m], bv[n], acc[m][n], 0, 0, 0);
  __builtin_amdgcn_s_setprio(0);
  __builtin_amdgcn_s_barrier();
  MEMFENCE;

  // ================= P1: read A-hi(4); stage B(T+2); vmcnt ================
#pragma unroll
  for (int m = 0; m < 4; ++m)
    av[m] = *(const i32x4*)(const void*)(
        &lds[b][(wm * 128 + 64 + m * 16 + lrow) * 64 + cs16]);
  if (MODE == 0) {
#pragma unroll
    for (int L = 0; L < 2; ++L)
      GLDS(Bg + (size_t)(sr + L * 64) * K_ + (T + 2) * BK + scs,
           &lds[b][BOFF + L * 4096 + tid * 16]);
  }
  __builtin_amdgcn_s_barrier();
  LGKM0;
  __builtin_amdgcn_s_setprio(1);
#pragma unroll
  for (int n = 0; n < 4; ++n)
#pragma unroll
    for (int m = 0; m < 4; ++m)
      acc[4 + m][n] = __builtin_amdgcn_mfma_i32_16x16x64_i8(av[m], bv[n], acc[4 + m][n], 0, 0, 0);
  __builtin_amdgcn_s_setprio(0);
  if (MODE == 0)      VM_WAIT(2);     // drains all tile-(T+1) data (ledger)
  else if (MODE == 1) VM_WAIT(0);     // drains A(NT-1)
  __builtin_amdgcn_s_barrier();
  MEMFENCE;
}

__global__ __launch_bounds__(256, 2) void gemmq_kernel(
    const signed char* __restrict__ A,   // Xq [M_][K_] i8
    const signed char* __restrict__ B,   // Wq [N_][K_] i8
    const float* __restrict__ sx, const float* __restrict__ sw,
    float* __restrict__ C)
{
  __shared__ signed char lds[2][24576];  // 48 KiB -> 2 WGs/CU

  // XCD-aware bijective swizzle (nwg = 1024, 1024 % 8 == 0)
  const int nwg = (M_ / BM) * (N_ / BN);
  const int bid = blockIdx.x;
  const int wg  = (bid % 8) * (nwg / 8) + bid / 8;
  const int tn  = wg % (N_ / BN);
  const int tm  = wg / (N_ / BN);
  const int brow = tm * BM, bcol = tn * BN;

  const int tid  = threadIdx.x;
  const int lane = tid & 63, w = tid >> 6;
  const int wm   = w >> 1, wn = w & 1;      // 2 (M) x 2 (N)
  const int lrow = lane & 15, hi2 = lane >> 4;
  const int cs16 = (hi2 ^ ((lrow >> 1) & 3)) * 16;       // swizzled read chunk
  const int sr  = tid >> 2;                               // staging row 0..63
  const int scs = ((tid & 3) ^ ((tid >> 3) & 3)) * 16;   // inv-swizzled source

  const signed char* Ag = A + (size_t)brow * K_;
  const signed char* Bg = B + (size_t)bcol * K_;

  i32x4 acc[8][4];
#pragma unroll
  for (int m = 0; m < 8; ++m)
#pragma unroll
    for (int n = 0; n < 4; ++n)
      acc[m][n] = i32x4{0, 0, 0, 0};

  // ---- prologue: [A(0):4][B(0):2][B(1):2]; vmcnt(2) drains tile 0 ----
#pragma unroll
  for (int L = 0; L < 4; ++L)
    GLDS(Ag + (size_t)(sr + L * 64) * K_ + scs, &lds[0][L * 4096 + tid * 16]);
#pragma unroll
  for (int L = 0; L < 2; ++L)
    GLDS(Bg + (size_t)(sr + L * 64) * K_ + scs, &lds[0][BOFF + L * 4096 + tid * 16]);
#pragma unroll
  for (int L = 0; L < 2; ++L)
    GLDS(Bg + (size_t)(sr + L * 64) * K_ + BK + scs, &lds[1][BOFF + L * 4096 + tid * 16]);
  VM_WAIT(2);
  __builtin_amdgcn_s_barrier();
  MEMFENCE;

  for (int T = 0; T < NT - 2; ++T)
    tile_step<0>(T, lds, acc, Ag, Bg, wm, wn, lrow, cs16, tid, sr, scs);
  tile_step<1>(NT - 2, lds, acc, Ag, Bg, wm, wn, lrow, cs16, tid, sr, scs);
  tile_step<2>(NT - 1, lds, acc, Ag, Bg, wm, wn, lrow, cs16, tid, sr, scs);

  // epilogue: C/D layout col = lane&15, row = (lane>>4)*4 + reg.
  // out = acc * sx[row] * sw[col].
  const int crow = brow + wm * 128 + hi2 * 4;
  const int ccol = bcol + wn * 64 + lrow;
  float swv[4];
#pragma unroll
  for (int n = 0; n < 4; ++n) swv[n] = sw[ccol + n * 16];
#pragma unroll
  for (int m = 0; m < 8; ++m)
#pragma unroll
    for (int r = 0; r < 4; ++r) {
      const int row = crow + m * 16 + r;
      const float sxv = sx[row];
#pragma unroll
      for (int n = 0; n < 4; ++n)
        C[(size_t)row * N_ + ccol + n * 16] = (float)acc[m][n][r] * sxv * swv[n];
    }
}

// ---------------------------------------------------------------------------
// Fallback (ws too small): fp32 tiled GEMM with on-the-fly dequant
// ---------------------------------------------------------------------------
__global__ __launch_bounds__(256) void fallback_kernel(
    const float* __restrict__ x, const float* __restrict__ cb,
    const float* __restrict__ scales, const int* __restrict__ idx,
    const int* __restrict__ signs, float* __restrict__ out)
{
  __shared__ float Xs[32][33];
  __shared__ float Ws[32][33];
  const int t = threadIdx.x;
  const int tx = t & 31, ty = t >> 5;
  const int brow = blockIdx.y * 32, bcol = blockIdx.x * 32;
  float acc[4] = {0.f, 0.f, 0.f, 0.f};

  for (int k0 = 0; k0 < K_; k0 += 32) {
    for (int l = t; l < 1024; l += 256) {
      const int r = l >> 5, c = l & 31;
      Xs[r][c] = x[(size_t)(brow + r) * K_ + k0 + c];
      const int n = bcol + r;
      const size_t flat = (size_t)n * K_ + (k0 + c);
      const int g = (int)(flat >> 3), j = (int)(flat & 7);
      float wv = cb[idx[g] * 8 + j] * scales[n];
      if (!((signs[g] >> (7 - j)) & 1)) wv = -wv;
      Ws[r][c] = wv;
    }
    __syncthreads();
#pragma unroll
    for (int kk = 0; kk < 32; ++kk) {
      const float wv = Ws[tx][kk];
      acc[0] += Xs[ty][kk] * wv;
      acc[1] += Xs[ty + 8][kk] * wv;
      acc[2] += Xs[ty + 16][kk] * wv;
      acc[3] += Xs[ty + 24][kk] * wv;
    }
    __syncthreads();
  }
#pragma unroll
  for (int q = 0; q < 4; ++q)
    out[(size_t)(brow + ty + 8 * q) * N_ + bcol + tx] = acc[q];
}

// ---------------------------------------------------------------------------
extern "C" void kernel_launch(void* const* d_in, const int* in_sizes, int n_in,
                              void* d_out, int out_size, void* d_ws, size_t ws_size,
                              hipStream_t stream)
{
  const float* x      = (const float*)d_in[0];
  const float* cb     = (const float*)d_in[1];
  const float* scales = (const float*)d_in[2];
  const int*   idx    = (const int*)d_in[3];
  const int*   signs  = (const int*)d_in[4];
  float* out = (float*)d_out;

  const size_t wq = (size_t)N_ * K_;        // 16.8 MB i8
  const size_t xq = (size_t)M_ * K_;        // 33.6 MB i8
  const size_t need = wq + xq + (N_ + M_) * sizeof(float);

  if (ws_size >= need) {
    signed char* Wq = (signed char*)d_ws;
    signed char* Xq = Wq + wq;
    float* swp = (float*)(Xq + xq);
    float* sxp = swp + N_;
    prep_kernel<<<N_ + M_, 256, 0, stream>>>(x, cb, scales, idx, signs, Wq, Xq, swp, sxp);
    gemmq_kernel<<<(M_ / BM) * (N_ / BN), 256, 0, stream>>>(Xq, Wq, sxp, swp, out);
  } else {
    fallback_kernel<<<dim3(N_ / 32, M_ / 32), 256, 0, stream>>>(x, cb, scales, idx, signs, out);
  }
}

// Round 16
// 187.501 us; speedup vs baseline: 1.0337x; 1.0337x over previous
//
#include <hip/hip_runtime.h>

// SymHQLinear: out[8192,4096] = x @ W^T; W[4096,4096] dequantized from
// codebook[4096,8] + per-row scales + packed sign bits.
// Strategy: per-row symmetric i8 quantization, mfma_i32_16x16x64_i8 GEMM,
// fp32 epilogue scales.  R16 = R11 + REGISTER PIPELINING: both P0 operand
// sets (A-lo, B) are read at the PREVIOUS tile's end, so MFMA0 issues with
// zero lgkm wait; A-hi reads fly under MFMA0.  Staging & vmcnt re-audited.
#define M_ 8192   // TOKENS
#define N_ 4096   // OUT
#define K_ 4096   // IN

typedef float f32x4 __attribute__((ext_vector_type(4)));
typedef int   i32x4 __attribute__((ext_vector_type(4)));

// ---------------------------------------------------------------------------
// Kernel 1 (fused prep): blocks [0, 4096): W row -> dequant, row-max, i8 + sw
//                        blocks [4096, 12288): X row -> row-max, i8 + sx
// ---------------------------------------------------------------------------
__device__ __forceinline__ unsigned pack4(const float* v, float inv) {
  unsigned r = 0;
#pragma unroll
  for (int j = 0; j < 4; ++j) {
    int q = (int)rintf(v[j] * inv);
    q = q < -127 ? -127 : (q > 127 ? 127 : q);
    r |= ((unsigned)(q & 0xff)) << (8 * j);
  }
  return r;
}

__global__ __launch_bounds__(256) void prep_kernel(
    const float* __restrict__ x, const float* __restrict__ cb,
    const float* __restrict__ scales, const int* __restrict__ idx,
    const int* __restrict__ signs,
    signed char* __restrict__ Wq, signed char* __restrict__ Xq,
    float* __restrict__ sw, float* __restrict__ sx)
{
  __shared__ float wred[4];
  const int b = blockIdx.x, t = threadIdx.x;

  if (b < N_) {
    const float s = scales[b];
    const int g0 = b * 512 + t, g1 = g0 + 256;
    const int c0 = idx[g0], c1 = idx[g1];
    const int sb0 = signs[g0], sb1 = signs[g1];
    const float* cv0 = cb + c0 * 8;
    const float* cv1 = cb + c1 * 8;
    float v[16];
    float mx = 0.f;
#pragma unroll
    for (int j = 0; j < 8; ++j) {
      float a = cv0[j] * s;
      if (!((sb0 >> (7 - j)) & 1)) a = -a;
      v[j] = a; mx = fmaxf(mx, fabsf(a));
    }
#pragma unroll
    for (int j = 0; j < 8; ++j) {
      float a = cv1[j] * s;
      if (!((sb1 >> (7 - j)) & 1)) a = -a;
      v[8 + j] = a; mx = fmaxf(mx, fabsf(a));
    }
#pragma unroll
    for (int off = 1; off < 64; off <<= 1) mx = fmaxf(mx, __shfl_xor(mx, off));
    if ((t & 63) == 0) wred[t >> 6] = mx;
    __syncthreads();
    mx = fmaxf(fmaxf(wred[0], wred[1]), fmaxf(wred[2], wred[3]));
    mx = fmaxf(mx, 1e-20f);
    const float inv = 127.0f / mx;
    if (t == 0) sw[b] = mx / 127.0f;
    uint2 o0 = {pack4(v, inv),     pack4(v + 4, inv)};
    uint2 o1 = {pack4(v + 8, inv), pack4(v + 12, inv)};
    *(uint2*)(Wq + (size_t)b * K_ + t * 8)        = o0;
    *(uint2*)(Wq + (size_t)b * K_ + 2048 + t * 8) = o1;
  } else {
    const int r = b - N_;
    const f32x4* px = (const f32x4*)(x + (size_t)r * K_ + t * 16);
    f32x4 a0 = px[0], a1 = px[1], a2 = px[2], a3 = px[3];
    float v[16];
#pragma unroll
    for (int j = 0; j < 4; ++j) { v[j] = a0[j]; v[4 + j] = a1[j]; v[8 + j] = a2[j]; v[12 + j] = a3[j]; }
    float mx = 0.f;
#pragma unroll
    for (int j = 0; j < 16; ++j) mx = fmaxf(mx, fabsf(v[j]));
#pragma unroll
    for (int off = 1; off < 64; off <<= 1) mx = fmaxf(mx, __shfl_xor(mx, off));
    if ((t & 63) == 0) wred[t >> 6] = mx;
    __syncthreads();
    mx = fmaxf(fmaxf(wred[0], wred[1]), fmaxf(wred[2], wred[3]));
    mx = fmaxf(mx, 1e-20f);
    const float inv = 127.0f / mx;
    if (t == 0) sx[r] = mx / 127.0f;
    uint4 o = {pack4(v, inv), pack4(v + 4, inv), pack4(v + 8, inv), pack4(v + 12, inv)};
    *(uint4*)(Xq + (size_t)r * K_ + t * 16) = o;
  }
}

// ---------------------------------------------------------------------------
// Kernel 2: 256x256x64 i8 GEMM, register-pipelined 2-phase.
// LDS 64 KiB: [2 bufs][A|B][256 x 64 i8]; swizzle c' = c ^ ((row>>1)&3)
// (conflict-free both-sides, R11-verified).
// Per tile T (b = T&1, nb = b^1), steady:
//   issue av1 <- A-hi(T) from b         (4 ds_read)
//   GLDS A(T+1) -> nb.A (2)             [nb.A readers confirmed T-1 + BAR2]
//   LGKM(4)  -> av0,bv (issued T-1 tail) served; av1 in flight
//   MFMA0: av0 x bv -> acc[0-3]  (16)   [zero-wait start]
//   LGKM(0)  -> av1 served
//   MFMA1: av1 x bv -> acc[4-7]  (16)
//   BAR#1    -> all waves' buf-b reads (av0,av1,bv) served
//   GLDS B(T+2) -> b.B (2)              [b.B reader bv(T) confirmed above]
//   vmcnt(2) -> oldest [B(T+1):2][A(T+1):2] drained = buf[T+1] complete
//   BAR#2    -> buf[T+1] visible
//   issue av0 <- A-lo(T+1), bv <- B(T+1) from nb   (8 ds_read, confirmed by
//   next tile's LGKM(4))
// Prologue: [A0:2][B0:2][B1:2], vmcnt(2), BAR, read av0/bv(0).
// T=NT-2: stage A only, vmcnt(0).  T=NT-1: MFMAs only.
// ---------------------------------------------------------------------------
#define BM 256
#define BN 256
#define BK 64
#define NT (K_ / BK)          // 64 K-tiles

#define GLDS(g, l) __builtin_amdgcn_global_load_lds( \
    (const __attribute__((address_space(1))) void*)(g), \
    (__attribute__((address_space(3))) void*)(l), 16, 0, 0)

#define LGKM_WAIT(n) do { \
    asm volatile("s_waitcnt lgkmcnt(" #n ")" ::: "memory"); \
    __builtin_amdgcn_sched_barrier(0); \
  } while (0)

#define VM_WAIT(n) asm volatile("s_waitcnt vmcnt(" #n ")" ::: "memory")
#define MEMFENCE asm volatile("" ::: "memory")

// MODE: 0 steady, 1 = T==NT-2, 2 = T==NT-1
template<int MODE>
__device__ __forceinline__ void tile_step(
    int T, signed char (*lds)[2][16384], i32x4 (&acc)[8][4],
    i32x4 (&av0)[4], i32x4 (&av1)[4], i32x4 (&bv)[4],
    const signed char* __restrict__ Ag,
    const signed char* __restrict__ Bg,
    int wm, int wn, int lrow, int cs16,   // cs16 = (hi2 ^ ((lrow>>1)&3)) * 16
    int tid, int sr, int scs)             // scs = inv-swizzled staging col
{
  const int b = T & 1, nb = b ^ 1;

  // ---- issue av1 <- A-hi(T); stage A(T+1) -> nb.A (safe per ledger) ----
#pragma unroll
  for (int m = 0; m < 4; ++m)
    av1[m] = *(const i32x4*)(const void*)(
        &lds[b][0][(wm * 128 + 64 + m * 16 + lrow) * 64 + cs16]);
  if (MODE <= 1) {
    GLDS(Ag + (size_t)(sr) * K_ + (T + 1) * BK + scs,       &lds[nb][0][tid * 16]);
    GLDS(Ag + (size_t)(128 + sr) * K_ + (T + 1) * BK + scs, &lds[nb][0][8192 + tid * 16]);
  }

  // ---- MFMA0: zero-wait (av0, bv confirmed by this wait counting only them)
  LGKM_WAIT(4);                        // av0+bv (oldest 8) served; av1 pending
  __builtin_amdgcn_s_setprio(1);
#pragma unroll
  for (int n = 0; n < 4; ++n)
#pragma unroll
    for (int m = 0; m < 4; ++m)
      acc[m][n] = __builtin_amdgcn_mfma_i32_16x16x64_i8(av0[m], bv[n], acc[m][n], 0, 0, 0);
  __builtin_amdgcn_s_setprio(0);

  LGKM_WAIT(0);                        // av1 served
  __builtin_amdgcn_s_setprio(1);
#pragma unroll
  for (int n = 0; n < 4; ++n)
#pragma unroll
    for (int m = 0; m < 4; ++m)
      acc[4 + m][n] = __builtin_amdgcn_mfma_i32_16x16x64_i8(av1[m], bv[n], acc[4 + m][n], 0, 0, 0);
  __builtin_amdgcn_s_setprio(0);

  if (MODE == 2) return;               // last tile: epilogue follows

  // ---- BAR#1: every wave's buf-b reads served -> b.B overwrite safe ----
  __builtin_amdgcn_s_barrier();
  MEMFENCE;
  if (MODE == 0) {
    GLDS(Bg + (size_t)(sr) * K_ + (T + 2) * BK + scs,       &lds[b][1][tid * 16]);
    GLDS(Bg + (size_t)(128 + sr) * K_ + (T + 2) * BK + scs, &lds[b][1][8192 + tid * 16]);
    VM_WAIT(2);                        // drains B(T+1)+A(T+1) = buf[T+1]
  } else {
    VM_WAIT(0);                        // T=NT-2: drain A(NT-1)+B(NT-1)
  }
  __builtin_amdgcn_s_barrier();        // BAR#2: buf[T+1] visible
  MEMFENCE;

  // ---- tail: pre-read next tile's P0 operands from nb ----
#pragma unroll
  for (int m = 0; m < 4; ++m)
    av0[m] = *(const i32x4*)(const void*)(
        &lds[nb][0][(wm * 128 + m * 16 + lrow) * 64 + cs16]);
#pragma unroll
  for (int n = 0; n < 4; ++n)
    bv[n] = *(const i32x4*)(const void*)(
        &lds[nb][1][(wn * 64 + n * 16 + lrow) * 64 + cs16]);
  // no wait here: next tile's LGKM_WAIT(4) confirms them
}

__global__ __launch_bounds__(512, 2) void gemmq_kernel(
    const signed char* __restrict__ A,   // Xq [M_][K_] i8
    const signed char* __restrict__ B,   // Wq [N_][K_] i8
    const float* __restrict__ sx, const float* __restrict__ sw,
    float* __restrict__ C)
{
  __shared__ signed char lds[2][2][16384];  // 64 KiB

  // XCD-aware bijective swizzle (nwg = 512, 512 % 8 == 0)
  const int nwg = (M_ / BM) * (N_ / BN);
  const int bid = blockIdx.x;
  const int wg  = (bid % 8) * (nwg / 8) + bid / 8;
  const int tn  = wg % (N_ / BN);
  const int tm  = wg / (N_ / BN);
  const int brow = tm * BM, bcol = tn * BN;

  const int tid  = threadIdx.x;
  const int lane = tid & 63, w = tid >> 6;
  const int wm   = w >> 2, wn = w & 3;      // 2 (M) x 4 (N)
  const int lrow = lane & 15, hi2 = lane >> 4;
  const int cs16 = (hi2 ^ ((lrow >> 1) & 3)) * 16;       // swizzled read chunk
  const int sr  = tid >> 2;
  const int scs = ((tid & 3) ^ ((tid >> 3) & 3)) * 16;   // inv-swizzled source

  const signed char* Ag = A + (size_t)brow * K_;
  const signed char* Bg = B + (size_t)bcol * K_;

  i32x4 acc[8][4];
#pragma unroll
  for (int m = 0; m < 8; ++m)
#pragma unroll
    for (int n = 0; n < 4; ++n)
      acc[m][n] = i32x4{0, 0, 0, 0};

  // ---- prologue: [A(0):2][B(0):2][B(1):2]; vmcnt(2) drains tile 0 ----
  GLDS(Ag + (size_t)(sr) * K_ + scs,            &lds[0][0][tid * 16]);
  GLDS(Ag + (size_t)(128 + sr) * K_ + scs,      &lds[0][0][8192 + tid * 16]);
  GLDS(Bg + (size_t)(sr) * K_ + scs,            &lds[0][1][tid * 16]);
  GLDS(Bg + (size_t)(128 + sr) * K_ + scs,      &lds[0][1][8192 + tid * 16]);
  GLDS(Bg + (size_t)(sr) * K_ + BK + scs,       &lds[1][1][tid * 16]);
  GLDS(Bg + (size_t)(128 + sr) * K_ + BK + scs, &lds[1][1][8192 + tid * 16]);
  VM_WAIT(2);
  __builtin_amdgcn_s_barrier();
  MEMFENCE;

  // pre-read tile-0 P0 operands (confirmed by tile-0's LGKM_WAIT(4))
  i32x4 av0[4], av1[4], bv[4];
#pragma unroll
  for (int m = 0; m < 4; ++m)
    av0[m] = *(const i32x4*)(const void*)(
        &lds[0][0][(wm * 128 + m * 16 + lrow) * 64 + cs16]);
#pragma unroll
  for (int n = 0; n < 4; ++n)
    bv[n] = *(const i32x4*)(const void*)(
        &lds[0][1][(wn * 64 + n * 16 + lrow) * 64 + cs16]);

  for (int T = 0; T < NT - 2; ++T)
    tile_step<0>(T, lds, acc, av0, av1, bv, Ag, Bg, wm, wn, lrow, cs16, tid, sr, scs);
  tile_step<1>(NT - 2, lds, acc, av0, av1, bv, Ag, Bg, wm, wn, lrow, cs16, tid, sr, scs);
  tile_step<2>(NT - 1, lds, acc, av0, av1, bv, Ag, Bg, wm, wn, lrow, cs16, tid, sr, scs);

  // epilogue: C/D layout col = lane&15, row = (lane>>4)*4 + reg.
  // out = acc * sx[row] * sw[col].
  const int crow = brow + wm * 128 + hi2 * 4;
  const int ccol = bcol + wn * 64 + lrow;
  float swv[4];
#pragma unroll
  for (int n = 0; n < 4; ++n) swv[n] = sw[ccol + n * 16];
#pragma unroll
  for (int m = 0; m < 8; ++m)
#pragma unroll
    for (int r = 0; r < 4; ++r) {
      const int row = crow + m * 16 + r;
      const float sxv = sx[row];
#pragma unroll
      for (int n = 0; n < 4; ++n)
        C[(size_t)row * N_ + ccol + n * 16] = (float)acc[m][n][r] * sxv * swv[n];
    }
}

// ---------------------------------------------------------------------------
// Fallback (ws too small): fp32 tiled GEMM with on-the-fly dequant
// ---------------------------------------------------------------------------
__global__ __launch_bounds__(256) void fallback_kernel(
    const float* __restrict__ x, const float* __restrict__ cb,
    const float* __restrict__ scales, const int* __restrict__ idx,
    const int* __restrict__ signs, float* __restrict__ out)
{
  __shared__ float Xs[32][33];
  __shared__ float Ws[32][33];
  const int t = threadIdx.x;
  const int tx = t & 31, ty = t >> 5;
  const int brow = blockIdx.y * 32, bcol = blockIdx.x * 32;
  float acc[4] = {0.f, 0.f, 0.f, 0.f};

  for (int k0 = 0; k0 < K_; k0 += 32) {
    for (int l = t; l < 1024; l += 256) {
      const int r = l >> 5, c = l & 31;
      Xs[r][c] = x[(size_t)(brow + r) * K_ + k0 + c];
      const int n = bcol + r;
      const size_t flat = (size_t)n * K_ + (k0 + c);
      const int g = (int)(flat >> 3), j = (int)(flat & 7);
      float wv = cb[idx[g] * 8 + j] * scales[n];
      if (!((signs[g] >> (7 - j)) & 1)) wv = -wv;
      Ws[r][c] = wv;
    }
    __syncthreads();
#pragma unroll
    for (int kk = 0; kk < 32; ++kk) {
      const float wv = Ws[tx][kk];
      acc[0] += Xs[ty][kk] * wv;
      acc[1] += Xs[ty + 8][kk] * wv;
      acc[2] += Xs[ty + 16][kk] * wv;
      acc[3] += Xs[ty + 24][kk] * wv;
    }
    __syncthreads();
  }
#pragma unroll
  for (int q = 0; q < 4; ++q)
    out[(size_t)(brow + ty + 8 * q) * N_ + bcol + tx] = acc[q];
}

// ---------------------------------------------------------------------------
extern "C" void kernel_launch(void* const* d_in, const int* in_sizes, int n_in,
                              void* d_out, int out_size, void* d_ws, size_t ws_size,
                              hipStream_t stream)
{
  const float* x      = (const float*)d_in[0];
  const float* cb     = (const float*)d_in[1];
  const float* scales = (const float*)d_in[2];
  const int*   idx    = (const int*)d_in[3];
  const int*   signs  = (const int*)d_in[4];
  float* out = (float*)d_out;

  const size_t wq = (size_t)N_ * K_;        // 16.8 MB i8
  const size_t xq = (size_t)M_ * K_;        // 33.6 MB i8
  const size_t need = wq + xq + (N_ + M_) * sizeof(float);

  if (ws_size >= need) {
    signed char* Wq = (signed char*)d_ws;
    signed char* Xq = Wq + wq;
    float* swp = (float*)(Xq + xq);
    float* sxp = swp + N_;
    prep_kernel<<<N_ + M_, 256, 0, stream>>>(x, cb, scales, idx, signs, Wq, Xq, swp, sxp);
    gemmq_kernel<<<(M_ / BM) * (N_ / BN), 512, 0, stream>>>(Xq, Wq, sxp, swp, out);
  } else {
    fallback_kernel<<<dim3(N_ / 32, M_ / 32), 256, 0, stream>>>(x, cb, scales, idx, signs, out);
  }
}

// Round 17
// 186.762 us; speedup vs baseline: 1.0378x; 1.0040x over previous
//
#include <hip/hip_runtime.h>

// SymHQLinear: out[8192,4096] = x @ W^T; W[4096,4096] dequantized from
// codebook[4096,8] + per-row scales + packed sign bits.
// Strategy: per-row symmetric i8 quantization, mfma_i32_16x16x64_i8 GEMM,
// fp32 epilogue scales.  R17 = R16 + tail-read coverage: MFMA1 moves after
// the barrier section and interleaves with the cross-buffer pre-reads
// (WAR-safe register reuse in program order, no extra registers), so the
// 8-read tail burst is covered by 16 MFMAs instead of being fully exposed.
#define M_ 8192   // TOKENS
#define N_ 4096   // OUT
#define K_ 4096   // IN

typedef float f32x4 __attribute__((ext_vector_type(4)));
typedef int   i32x4 __attribute__((ext_vector_type(4)));

// ---------------------------------------------------------------------------
// Kernel 1 (fused prep): blocks [0, 4096): W row -> dequant, row-max, i8 + sw
//                        blocks [4096, 12288): X row -> row-max, i8 + sx
// ---------------------------------------------------------------------------
__device__ __forceinline__ unsigned pack4(const float* v, float inv) {
  unsigned r = 0;
#pragma unroll
  for (int j = 0; j < 4; ++j) {
    int q = (int)rintf(v[j] * inv);
    q = q < -127 ? -127 : (q > 127 ? 127 : q);
    r |= ((unsigned)(q & 0xff)) << (8 * j);
  }
  return r;
}

__global__ __launch_bounds__(256) void prep_kernel(
    const float* __restrict__ x, const float* __restrict__ cb,
    const float* __restrict__ scales, const int* __restrict__ idx,
    const int* __restrict__ signs,
    signed char* __restrict__ Wq, signed char* __restrict__ Xq,
    float* __restrict__ sw, float* __restrict__ sx)
{
  __shared__ float wred[4];
  const int b = blockIdx.x, t = threadIdx.x;

  if (b < N_) {
    const float s = scales[b];
    const int g0 = b * 512 + t, g1 = g0 + 256;
    const int c0 = idx[g0], c1 = idx[g1];
    const int sb0 = signs[g0], sb1 = signs[g1];
    const float* cv0 = cb + c0 * 8;
    const float* cv1 = cb + c1 * 8;
    float v[16];
    float mx = 0.f;
#pragma unroll
    for (int j = 0; j < 8; ++j) {
      float a = cv0[j] * s;
      if (!((sb0 >> (7 - j)) & 1)) a = -a;
      v[j] = a; mx = fmaxf(mx, fabsf(a));
    }
#pragma unroll
    for (int j = 0; j < 8; ++j) {
      float a = cv1[j] * s;
      if (!((sb1 >> (7 - j)) & 1)) a = -a;
      v[8 + j] = a; mx = fmaxf(mx, fabsf(a));
    }
#pragma unroll
    for (int off = 1; off < 64; off <<= 1) mx = fmaxf(mx, __shfl_xor(mx, off));
    if ((t & 63) == 0) wred[t >> 6] = mx;
    __syncthreads();
    mx = fmaxf(fmaxf(wred[0], wred[1]), fmaxf(wred[2], wred[3]));
    mx = fmaxf(mx, 1e-20f);
    const float inv = 127.0f / mx;
    if (t == 0) sw[b] = mx / 127.0f;
    uint2 o0 = {pack4(v, inv),     pack4(v + 4, inv)};
    uint2 o1 = {pack4(v + 8, inv), pack4(v + 12, inv)};
    *(uint2*)(Wq + (size_t)b * K_ + t * 8)        = o0;
    *(uint2*)(Wq + (size_t)b * K_ + 2048 + t * 8) = o1;
  } else {
    const int r = b - N_;
    const f32x4* px = (const f32x4*)(x + (size_t)r * K_ + t * 16);
    f32x4 a0 = px[0], a1 = px[1], a2 = px[2], a3 = px[3];
    float v[16];
#pragma unroll
    for (int j = 0; j < 4; ++j) { v[j] = a0[j]; v[4 + j] = a1[j]; v[8 + j] = a2[j]; v[12 + j] = a3[j]; }
    float mx = 0.f;
#pragma unroll
    for (int j = 0; j < 16; ++j) mx = fmaxf(mx, fabsf(v[j]));
#pragma unroll
    for (int off = 1; off < 64; off <<= 1) mx = fmaxf(mx, __shfl_xor(mx, off));
    if ((t & 63) == 0) wred[t >> 6] = mx;
    __syncthreads();
    mx = fmaxf(fmaxf(wred[0], wred[1]), fmaxf(wred[2], wred[3]));
    mx = fmaxf(mx, 1e-20f);
    const float inv = 127.0f / mx;
    if (t == 0) sx[r] = mx / 127.0f;
    uint4 o = {pack4(v, inv), pack4(v + 4, inv), pack4(v + 8, inv), pack4(v + 12, inv)};
    *(uint4*)(Xq + (size_t)r * K_ + t * 16) = o;
  }
}

// ---------------------------------------------------------------------------
// Kernel 2: 256x256x64 i8 GEMM, register-pipelined with tail-read coverage.
// LDS 64 KiB: [2 bufs][A|B][256 x 64 i8]; swizzle c' = c ^ ((row>>1)&3).
// Per tile T (b = T&1, nb = b^1), steady:
//   1 issue av1 <- b.A-hi (4)
//   2 GLDS A(T+1) -> nb.A (2)
//   3 LGKM(4)  -> av0,bv (prev tail) served
//   4 MFMA0: av0 x bv (16)
//   5 LGKM(0)  -> av1 served; ALL b-buf reads now served
//   6 BAR#1
//   7 GLDS B(T+2) -> b.B (2)
//   8 vmcnt(2) -> B(T+1)+A(T+1) drained
//   9 BAR#2 -> buf[T+1] visible
//  10 issue av0' <- nb.A-lo (4)      [av0 dead since step 4]
//  11 MFMA1a: av1 x bv[0,1] (8)     [covers step-10 reads]
//  12 issue bv'[0,1] <- nb.B (2)    [bv[0,1] dead since step 11]
//  13 MFMA1b: av1 x bv[2,3] (8)     [covers step-12 reads]
//  14 issue bv'[2,3] <- nb.B (2)    [bv[2,3] dead since step 13]
// Next tile's LGKM(4) drains av0'+bv' (8), leaving av1' (4).  Order pinned
// with sched_barrier(0) (rule #18: reg-only MFMAs hoist past barriers).
// Prologue: [A0:2][B0:2][B1:2], vmcnt(2), BAR, pre-read av0/bv(0).
// T=NT-2: stage A only, vmcnt(0).  T=NT-1: MFMA0+MFMA1 only, no tail.
// ---------------------------------------------------------------------------
#define BM 256
#define BN 256
#define BK 64
#define NT (K_ / BK)          // 64 K-tiles

#define GLDS(g, l) __builtin_amdgcn_global_load_lds( \
    (const __attribute__((address_space(1))) void*)(g), \
    (__attribute__((address_space(3))) void*)(l), 16, 0, 0)

#define LGKM_WAIT(n) do { \
    asm volatile("s_waitcnt lgkmcnt(" #n ")" ::: "memory"); \
    __builtin_amdgcn_sched_barrier(0); \
  } while (0)

#define VM_WAIT(n) asm volatile("s_waitcnt vmcnt(" #n ")" ::: "memory")
#define MEMFENCE asm volatile("" ::: "memory")
#define SBAR0 __builtin_amdgcn_sched_barrier(0)

// MODE: 0 steady, 1 = T==NT-2, 2 = T==NT-1
template<int MODE>
__device__ __forceinline__ void tile_step(
    int T, signed char (*lds)[2][16384], i32x4 (&acc)[8][4],
    i32x4 (&av0)[4], i32x4 (&av1)[4], i32x4 (&bv)[4],
    const signed char* __restrict__ Ag,
    const signed char* __restrict__ Bg,
    int wm, int wn, int lrow, int cs16,   // cs16 = (hi2 ^ ((lrow>>1)&3)) * 16
    int tid, int sr, int scs)             // scs = inv-swizzled staging col
{
  const int b = T & 1, nb = b ^ 1;

  // ---- 1: issue av1 <- A-hi(T);  2: stage A(T+1) -> nb.A ----
#pragma unroll
  for (int m = 0; m < 4; ++m)
    av1[m] = *(const i32x4*)(const void*)(
        &lds[b][0][(wm * 128 + 64 + m * 16 + lrow) * 64 + cs16]);
  if (MODE <= 1) {
    GLDS(Ag + (size_t)(sr) * K_ + (T + 1) * BK + scs,       &lds[nb][0][tid * 16]);
    GLDS(Ag + (size_t)(128 + sr) * K_ + (T + 1) * BK + scs, &lds[nb][0][8192 + tid * 16]);
  }

  // ---- 3-4: MFMA0 zero-wait (av0, bv confirmed; av1 stays in flight) ----
  LGKM_WAIT(4);
  __builtin_amdgcn_s_setprio(1);
#pragma unroll
  for (int n = 0; n < 4; ++n)
#pragma unroll
    for (int m = 0; m < 4; ++m)
      acc[m][n] = __builtin_amdgcn_mfma_i32_16x16x64_i8(av0[m], bv[n], acc[m][n], 0, 0, 0);
  __builtin_amdgcn_s_setprio(0);

  LGKM_WAIT(0);                        // 5: av1 served; all b-buf reads done

  if (MODE == 2) {
    // final tile: complete MFMA1 here, no barriers/stages/tail
    __builtin_amdgcn_s_setprio(1);
#pragma unroll
    for (int n = 0; n < 4; ++n)
#pragma unroll
      for (int m = 0; m < 4; ++m)
        acc[4 + m][n] = __builtin_amdgcn_mfma_i32_16x16x64_i8(av1[m], bv[n], acc[4 + m][n], 0, 0, 0);
    __builtin_amdgcn_s_setprio(0);
    return;
  }

  // ---- 6-9: barrier section ----
  __builtin_amdgcn_s_barrier();        // BAR#1: b-buf overwrite safe
  MEMFENCE;
  if (MODE == 0) {
    GLDS(Bg + (size_t)(sr) * K_ + (T + 2) * BK + scs,       &lds[b][1][tid * 16]);
    GLDS(Bg + (size_t)(128 + sr) * K_ + (T + 2) * BK + scs, &lds[b][1][8192 + tid * 16]);
    VM_WAIT(2);                        // drains B(T+1)+A(T+1) = buf[T+1]
  } else {
    VM_WAIT(0);                        // T=NT-2: full drain
  }
  __builtin_amdgcn_s_barrier();        // BAR#2: buf[T+1] visible
  MEMFENCE;
  SBAR0;

  // ---- 10: issue av0' <- nb.A-lo (av0 dead since MFMA0) ----
#pragma unroll
  for (int m = 0; m < 4; ++m)
    av0[m] = *(const i32x4*)(const void*)(
        &lds[nb][0][(wm * 128 + m * 16 + lrow) * 64 + cs16]);
  SBAR0;

  // ---- 11: MFMA1a: av1 x bv[0,1] (covers av0' reads) ----
  __builtin_amdgcn_s_setprio(1);
#pragma unroll
  for (int n = 0; n < 2; ++n)
#pragma unroll
    for (int m = 0; m < 4; ++m)
      acc[4 + m][n] = __builtin_amdgcn_mfma_i32_16x16x64_i8(av1[m], bv[n], acc[4 + m][n], 0, 0, 0);
  __builtin_amdgcn_s_setprio(0);
  SBAR0;

  // ---- 12: issue bv'[0,1] (bv[0,1] dead since MFMA1a) ----
#pragma unroll
  for (int n = 0; n < 2; ++n)
    bv[n] = *(const i32x4*)(const void*)(
        &lds[nb][1][(wn * 64 + n * 16 + lrow) * 64 + cs16]);
  SBAR0;

  // ---- 13: MFMA1b: av1 x bv[2,3] (covers bv'[0,1] reads) ----
  __builtin_amdgcn_s_setprio(1);
#pragma unroll
  for (int n = 2; n < 4; ++n)
#pragma unroll
    for (int m = 0; m < 4; ++m)
      acc[4 + m][n] = __builtin_amdgcn_mfma_i32_16x16x64_i8(av1[m], bv[n], acc[4 + m][n], 0, 0, 0);
  __builtin_amdgcn_s_setprio(0);
  SBAR0;

  // ---- 14: issue bv'[2,3] ----
#pragma unroll
  for (int n = 2; n < 4; ++n)
    bv[n] = *(const i32x4*)(const void*)(
        &lds[nb][1][(wn * 64 + n * 16 + lrow) * 64 + cs16]);
  // next tile's LGKM_WAIT(4) drains av0'(4)+bv'(4), leaving av1'(4)
}

__global__ __launch_bounds__(512, 2) void gemmq_kernel(
    const signed char* __restrict__ A,   // Xq [M_][K_] i8
    const signed char* __restrict__ B,   // Wq [N_][K_] i8
    const float* __restrict__ sx, const float* __restrict__ sw,
    float* __restrict__ C)
{
  __shared__ signed char lds[2][2][16384];  // 64 KiB

  // XCD-aware bijective swizzle (nwg = 512, 512 % 8 == 0)
  const int nwg = (M_ / BM) * (N_ / BN);
  const int bid = blockIdx.x;
  const int wg  = (bid % 8) * (nwg / 8) + bid / 8;
  const int tn  = wg % (N_ / BN);
  const int tm  = wg / (N_ / BN);
  const int brow = tm * BM, bcol = tn * BN;

  const int tid  = threadIdx.x;
  const int lane = tid & 63, w = tid >> 6;
  const int wm   = w >> 2, wn = w & 3;      // 2 (M) x 4 (N)
  const int lrow = lane & 15, hi2 = lane >> 4;
  const int cs16 = (hi2 ^ ((lrow >> 1) & 3)) * 16;       // swizzled read chunk
  const int sr  = tid >> 2;
  const int scs = ((tid & 3) ^ ((tid >> 3) & 3)) * 16;   // inv-swizzled source

  const signed char* Ag = A + (size_t)brow * K_;
  const signed char* Bg = B + (size_t)bcol * K_;

  i32x4 acc[8][4];
#pragma unroll
  for (int m = 0; m < 8; ++m)
#pragma unroll
    for (int n = 0; n < 4; ++n)
      acc[m][n] = i32x4{0, 0, 0, 0};

  // ---- prologue: [A(0):2][B(0):2][B(1):2]; vmcnt(2) drains tile 0 ----
  GLDS(Ag + (size_t)(sr) * K_ + scs,            &lds[0][0][tid * 16]);
  GLDS(Ag + (size_t)(128 + sr) * K_ + scs,      &lds[0][0][8192 + tid * 16]);
  GLDS(Bg + (size_t)(sr) * K_ + scs,            &lds[0][1][tid * 16]);
  GLDS(Bg + (size_t)(128 + sr) * K_ + scs,      &lds[0][1][8192 + tid * 16]);
  GLDS(Bg + (size_t)(sr) * K_ + BK + scs,       &lds[1][1][tid * 16]);
  GLDS(Bg + (size_t)(128 + sr) * K_ + BK + scs, &lds[1][1][8192 + tid * 16]);
  VM_WAIT(2);
  __builtin_amdgcn_s_barrier();
  MEMFENCE;

  // pre-read tile-0 P0 operands (confirmed by tile-0's LGKM_WAIT(4))
  i32x4 av0[4], av1[4], bv[4];
#pragma unroll
  for (int m = 0; m < 4; ++m)
    av0[m] = *(const i32x4*)(const void*)(
        &lds[0][0][(wm * 128 + m * 16 + lrow) * 64 + cs16]);
#pragma unroll
  for (int n = 0; n < 4; ++n)
    bv[n] = *(const i32x4*)(const void*)(
        &lds[0][1][(wn * 64 + n * 16 + lrow) * 64 + cs16]);

  for (int T = 0; T < NT - 2; ++T)
    tile_step<0>(T, lds, acc, av0, av1, bv, Ag, Bg, wm, wn, lrow, cs16, tid, sr, scs);
  tile_step<1>(NT - 2, lds, acc, av0, av1, bv, Ag, Bg, wm, wn, lrow, cs16, tid, sr, scs);
  tile_step<2>(NT - 1, lds, acc, av0, av1, bv, Ag, Bg, wm, wn, lrow, cs16, tid, sr, scs);

  // epilogue: C/D layout col = lane&15, row = (lane>>4)*4 + reg.
  // out = acc * sx[row] * sw[col].
  const int crow = brow + wm * 128 + hi2 * 4;
  const int ccol = bcol + wn * 64 + lrow;
  float swv[4];
#pragma unroll
  for (int n = 0; n < 4; ++n) swv[n] = sw[ccol + n * 16];
#pragma unroll
  for (int m = 0; m < 8; ++m)
#pragma unroll
    for (int r = 0; r < 4; ++r) {
      const int row = crow + m * 16 + r;
      const float sxv = sx[row];
#pragma unroll
      for (int n = 0; n < 4; ++n)
        C[(size_t)row * N_ + ccol + n * 16] = (float)acc[m][n][r] * sxv * swv[n];
    }
}

// ---------------------------------------------------------------------------
// Fallback (ws too small): fp32 tiled GEMM with on-the-fly dequant
// ---------------------------------------------------------------------------
__global__ __launch_bounds__(256) void fallback_kernel(
    const float* __restrict__ x, const float* __restrict__ cb,
    const float* __restrict__ scales, const int* __restrict__ idx,
    const int* __restrict__ signs, float* __restrict__ out)
{
  __shared__ float Xs[32][33];
  __shared__ float Ws[32][33];
  const int t = threadIdx.x;
  const int tx = t & 31, ty = t >> 5;
  const int brow = blockIdx.y * 32, bcol = blockIdx.x * 32;
  float acc[4] = {0.f, 0.f, 0.f, 0.f};

  for (int k0 = 0; k0 < K_; k0 += 32) {
    for (int l = t; l < 1024; l += 256) {
      const int r = l >> 5, c = l & 31;
      Xs[r][c] = x[(size_t)(brow + r) * K_ + k0 + c];
      const int n = bcol + r;
      const size_t flat = (size_t)n * K_ + (k0 + c);
      const int g = (int)(flat >> 3), j = (int)(flat & 7);
      float wv = cb[idx[g] * 8 + j] * scales[n];
      if (!((signs[g] >> (7 - j)) & 1)) wv = -wv;
      Ws[r][c] = wv;
    }
    __syncthreads();
#pragma unroll
    for (int kk = 0; kk < 32; ++kk) {
      const float wv = Ws[tx][kk];
      acc[0] += Xs[ty][kk] * wv;
      acc[1] += Xs[ty + 8][kk] * wv;
      acc[2] += Xs[ty + 16][kk] * wv;
      acc[3] += Xs[ty + 24][kk] * wv;
    }
    __syncthreads();
  }
#pragma unroll
  for (int q = 0; q < 4; ++q)
    out[(size_t)(brow + ty + 8 * q) * N_ + bcol + tx] = acc[q];
}

// ---------------------------------------------------------------------------
extern "C" void kernel_launch(void* const* d_in, const int* in_sizes, int n_in,
                              void* d_out, int out_size, void* d_ws, size_t ws_size,
                              hipStream_t stream)
{
  const float* x      = (const float*)d_in[0];
  const float* cb     = (const float*)d_in[1];
  const float* scales = (const float*)d_in[2];
  const int*   idx    = (const int*)d_in[3];
  const int*   signs  = (const int*)d_in[4];
  float* out = (float*)d_out;

  const size_t wq = (size_t)N_ * K_;        // 16.8 MB i8
  const size_t xq = (size_t)M_ * K_;        // 33.6 MB i8
  const size_t need = wq + xq + (N_ + M_) * sizeof(float);

  if (ws_size >= need) {
    signed char* Wq = (signed char*)d_ws;
    signed char* Xq = Wq + wq;
    float* swp = (float*)(Xq + xq);
    float* sxp = swp + N_;
    prep_kernel<<<N_ + M_, 256, 0, stream>>>(x, cb, scales, idx, signs, Wq, Xq, swp, sxp);
    gemmq_kernel<<<(M_ / BM) * (N_ / BN), 512, 0, stream>>>(Xq, Wq, sxp, swp, out);
  } else {
    fallback_kernel<<<dim3(N_ / 32, M_ / 32), 256, 0, stream>>>(x, cb, scales, idx, signs, out);
  }
}